// Round 3
// baseline (317.995 us; speedup 1.0000x reference)
//
#include <hip/hip_runtime.h>
#include <hip/hip_bf16.h>

#define S_LEN 2048
#define NB    32      // batch
#define EMB   1024
#define ATT   512
#define HID   1024

typedef float f32x4  __attribute__((ext_vector_type(4)));
typedef short s16x4  __attribute__((ext_vector_type(4)));
typedef short s16x8  __attribute__((ext_vector_type(8)));

static __device__ __forceinline__ short f2bf(float f) {
    return __builtin_bit_cast(short, __float2bfloat16(f));
}
static __device__ __forceinline__ float bf2f(unsigned short u) {
    unsigned int x = ((unsigned int)u) << 16;
    return __builtin_bit_cast(float, x);
}
static __device__ __forceinline__ float tanh_fast(float x) {
    float e = __expf(2.0f * x);
    return 1.0f - 2.0f / (e + 1.0f);
}

#define GLOAD_LDS16(gp, lp)                                                   \
    __builtin_amdgcn_global_load_lds(                                         \
        (const __attribute__((address_space(1))) void*)(gp),                  \
        (__attribute__((address_space(3))) void*)(uintptr_t)(lp), 16, 0, 0)

// ---------------- K0: emb f32 -> bf16 (layout preserved [S][B][E])
__global__ void k_cvt(const float* __restrict__ in, unsigned short* __restrict__ out) {
    size_t base = ((size_t)blockIdx.x * 256 + threadIdx.x) * 8;
    const size_t stride = (size_t)2048 * 256 * 8;
#pragma unroll 4
    for (int it = 0; it < 16; ++it, base += stride) {
        f32x4 x0 = *(const f32x4*)(in + base);
        f32x4 x1 = *(const f32x4*)(in + base + 4);
        s16x8 r;
        r[0] = f2bf(x0[0]); r[1] = f2bf(x0[1]);
        r[2] = f2bf(x0[2]); r[3] = f2bf(x0[3]);
        r[4] = f2bf(x1[0]); r[5] = f2bf(x1[1]);
        r[6] = f2bf(x1[2]); r[7] = f2bf(x1[3]);
        *(s16x8*)(out + base) = r;
    }
}

// ---------------- K1: hid_comb[b][a] = hid[b,:]@W_hid[:,a] + b_hid[a] + b_emb[a]
__global__ void k_hidcomb(const float* __restrict__ hid,
                          const float* __restrict__ W_hid,
                          const float* __restrict__ b_hid,
                          const float* __restrict__ b_emb,
                          float* __restrict__ hid_comb) {
    int gid = blockIdx.x * 256 + threadIdx.x;   // 32*512 = 16384
    int b = gid >> 9, a = gid & 511;
    const float* hr = hid + b * HID;
    float acc = 0.f;
#pragma unroll 4
    for (int k = 0; k < HID; ++k) acc += hr[k] * W_hid[k * ATT + a];
    hid_comb[gid] = acc + b_hid[a] + b_emb[a];
}

// ---------------- K2: W_T[a][k] = bf16(W_emb[k][a])
__global__ void k_wt(const float* __restrict__ W, unsigned short* __restrict__ WT) {
    __shared__ float tile[32][33];
    int k0 = blockIdx.x * 32, a0 = blockIdx.y * 32;
    int tx = threadIdx.x, ty = threadIdx.y;     // 32 x 8
#pragma unroll
    for (int i = 0; i < 32; i += 8)
        tile[ty + i][tx] = W[(size_t)(k0 + ty + i) * ATT + a0 + tx];
    __syncthreads();
#pragma unroll
    for (int i = 0; i < 32; i += 8)
        WT[(size_t)(a0 + ty + i) * HID + k0 + tx] =
            (unsigned short)f2bf(tile[tx][ty + i]);
}

// ---------------- K3 (bf16 path): m97-style 128x128 GEMM, both operands via
// global_load_lds16 (pre-swizzled source, linear LDS dest, swizzled reads),
// fused tanh + dot(att_v) epilogue. 4 waves x (32x128) -> no cross-wave combine.
__global__ __launch_bounds__(256) void k_gemm_bf16(
        const unsigned short* __restrict__ embB,
        const unsigned short* __restrict__ WT,
        const float* __restrict__ hid_comb,
        const float* __restrict__ att_v,
        float* __restrict__ part) {           // part[nt][b][s], nt=0..3
    __shared__ __align__(16) unsigned short lA[128 * 32];  // 8KB
    __shared__ __align__(16) unsigned short lB[128 * 32];  // 8KB

    // XCD swizzle: 2048 wgs, 8 XCDs; all 4 n-tiles of an m-panel on one XCD.
    int bid = blockIdx.x;
    int t2 = (bid & 7) * 256 + (bid >> 3);
    int mt = t2 >> 2, nt = t2 & 3;
    int m0 = mt * 128, n0 = nt * 128;

    int tid  = threadIdx.x;
    int lane = tid & 63, wave = tid >> 6;
    int row_l = lane & 15;        // fragment row (A) / col (B,D)
    int kg    = lane >> 4;        // k-group: k = kg*8 + i

    // staging map (identical for A and B): chunk c = j*256+tid covers 16B
    int rowc[2], srcch[2], dstb[2];
#pragma unroll
    for (int j = 0; j < 2; ++j) {
        int c = j * 256 + tid;
        int r = c >> 2, ch = c & 3;
        rowc[j]  = r;
        srcch[j] = ch ^ ((r >> 1) & 3);
        dstb[j]  = c * 16;
    }
    const unsigned short* aB = embB + (size_t)m0 * EMB;
    const unsigned short* bB = WT   + (size_t)n0 * HID;

    // fragment read offsets (swizzled)
    int aoff[2], boff[8];
#pragma unroll
    for (int mf = 0; mf < 2; ++mf) {
        int row = wave * 32 + mf * 16 + row_l;
        aoff[mf] = row * 64 + ((kg ^ ((row >> 1) & 3)) * 16);
    }
#pragma unroll
    for (int nf = 0; nf < 8; ++nf) {
        int row = nf * 16 + row_l;
        boff[nf] = row * 64 + ((kg ^ ((row >> 1) & 3)) * 16);
    }

    f32x4 acc[2][8] = {};

    for (int kk = 0; kk < EMB; kk += 32) {
#pragma unroll
        for (int j = 0; j < 2; ++j)
            GLOAD_LDS16(aB + (size_t)rowc[j] * EMB + kk + srcch[j] * 8,
                        (char*)lA + dstb[j]);
#pragma unroll
        for (int j = 0; j < 2; ++j)
            GLOAD_LDS16(bB + (size_t)rowc[j] * HID + kk + srcch[j] * 8,
                        (char*)lB + dstb[j]);
        __syncthreads();   // drains vmcnt: tiles ready

        s16x8 af[2], bf[8];
#pragma unroll
        for (int mf = 0; mf < 2; ++mf)
            af[mf] = *(const s16x8*)((const char*)lA + aoff[mf]);
#pragma unroll
        for (int nf = 0; nf < 8; ++nf)
            bf[nf] = *(const s16x8*)((const char*)lB + boff[nf]);
#pragma unroll
        for (int mf = 0; mf < 2; ++mf)
#pragma unroll
            for (int nf = 0; nf < 8; ++nf)
                acc[mf][nf] = __builtin_amdgcn_mfma_f32_16x16x32_bf16(
                    af[mf], bf[nf], acc[mf][nf], 0, 0, 0);
        __syncthreads();   // all reads done before next stage overwrites
    }

    // ---- epilogue
    float vv[8];
#pragma unroll
    for (int nf = 0; nf < 8; ++nf)
        vv[nf] = att_v[n0 + nf * 16 + row_l];

#pragma unroll
    for (int mf = 0; mf < 2; ++mf) {
#pragma unroll
        for (int j = 0; j < 4; ++j) {
            int m = m0 + wave * 32 + mf * 16 + kg * 4 + j;   // D row
            int b = m & 31;
            int s = m >> 5;
            const float* ad = hid_comb + b * ATT + n0;
            float sum = 0.f;
#pragma unroll
            for (int nf = 0; nf < 8; ++nf) {
                float x = acc[mf][nf][j] + ad[nf * 16 + row_l];
                sum += tanh_fast(x) * vv[nf];
            }
#pragma unroll
            for (int d = 1; d < 16; d <<= 1)
                sum += __shfl_xor(sum, d, 64);
            if (row_l == 0)
                part[nt * (NB * S_LEN) + b * S_LEN + s] = sum;
        }
    }
}

// ---------------- K3 fallback (f32 A reg-stage, round-2 version)
__global__ __launch_bounds__(256) void k_gemm_f32(
        const float* __restrict__ emb,
        const unsigned short* __restrict__ WT,
        const float* __restrict__ hid_comb,
        const float* __restrict__ att_v,
        float* __restrict__ part) {
    __shared__ __align__(16) unsigned short lA[128 * 32];
    __shared__ __align__(16) unsigned short lB[128 * 32];
    int bid = blockIdx.x;
    int t2 = (bid & 7) * 256 + (bid >> 3);
    int mt = t2 >> 2, nt = t2 & 3;
    int m0 = mt * 128, n0 = nt * 128;
    int tid  = threadIdx.x;
    int lane = tid & 63, wave = tid >> 6;
    int row_l = lane & 15, kg = lane >> 4;

    int ar[4], ac[4], awoff[4];
#pragma unroll
    for (int i = 0; i < 4; ++i) {
        int ci = i * 256 + tid;
        ar[i] = ci >> 3;
        ac[i] = (ci & 7) * 4;
        int slot = ci & 7;
        int ch = (slot >> 1) ^ ((ar[i] >> 1) & 3);
        awoff[i] = ar[i] * 64 + ch * 16 + (slot & 1) * 8;
    }
    const float* abase = emb + (size_t)m0 * EMB;
    const unsigned short* bbase = WT + (size_t)n0 * HID;
    int brow[2], bsrcch[2], bdst[2];
#pragma unroll
    for (int j = 0; j < 2; ++j) {
        int c = j * 256 + tid;
        int row = c >> 2, ch = c & 3;
        brow[j] = row; bsrcch[j] = ch ^ ((row >> 1) & 3); bdst[j] = c * 16;
    }
    int aoff[2], boff[8];
#pragma unroll
    for (int mf = 0; mf < 2; ++mf) {
        int row = wave * 32 + mf * 16 + row_l;
        aoff[mf] = row * 64 + ((kg ^ ((row >> 1) & 3)) * 16);
    }
#pragma unroll
    for (int nf = 0; nf < 8; ++nf) {
        int row = nf * 16 + row_l;
        boff[nf] = row * 64 + ((kg ^ ((row >> 1) & 3)) * 16);
    }
    f32x4 acc[2][8] = {};
    f32x4 areg[4];
#pragma unroll
    for (int i = 0; i < 4; ++i)
        areg[i] = *(const f32x4*)(abase + (size_t)ar[i] * EMB + ac[i]);
    for (int kk = 0; kk < EMB; kk += 32) {
        __syncthreads();
#pragma unroll
        for (int i = 0; i < 4; ++i) {
            s16x4 w;
            w[0] = f2bf(areg[i][0]); w[1] = f2bf(areg[i][1]);
            w[2] = f2bf(areg[i][2]); w[3] = f2bf(areg[i][3]);
            *(s16x4*)((char*)lA + awoff[i]) = w;
        }
#pragma unroll
        for (int j = 0; j < 2; ++j)
            GLOAD_LDS16(bbase + (size_t)brow[j] * HID + kk + bsrcch[j] * 8,
                        (char*)lB + bdst[j]);
        __syncthreads();
        int kn = (kk + 32 < EMB) ? kk + 32 : 0;
#pragma unroll
        for (int i = 0; i < 4; ++i)
            areg[i] = *(const f32x4*)(abase + (size_t)ar[i] * EMB + kn + ac[i]);
        s16x8 af[2], bf[8];
#pragma unroll
        for (int mf = 0; mf < 2; ++mf)
            af[mf] = *(const s16x8*)((const char*)lA + aoff[mf]);
#pragma unroll
        for (int nf = 0; nf < 8; ++nf)
            bf[nf] = *(const s16x8*)((const char*)lB + boff[nf]);
#pragma unroll
        for (int mf = 0; mf < 2; ++mf)
#pragma unroll
            for (int nf = 0; nf < 8; ++nf)
                acc[mf][nf] = __builtin_amdgcn_mfma_f32_16x16x32_bf16(
                    af[mf], bf[nf], acc[mf][nf], 0, 0, 0);
    }
    float vv[8];
#pragma unroll
    for (int nf = 0; nf < 8; ++nf)
        vv[nf] = att_v[n0 + nf * 16 + row_l];
#pragma unroll
    for (int mf = 0; mf < 2; ++mf) {
#pragma unroll
        for (int j = 0; j < 4; ++j) {
            int m = m0 + wave * 32 + mf * 16 + kg * 4 + j;
            int b = m & 31;
            int s = m >> 5;
            const float* ad = hid_comb + b * ATT + n0;
            float sum = 0.f;
#pragma unroll
            for (int nf = 0; nf < 8; ++nf) {
                float x = acc[mf][nf][j] + ad[nf * 16 + row_l];
                sum += tanh_fast(x) * vv[nf];
            }
#pragma unroll
            for (int d = 1; d < 16; d <<= 1)
                sum += __shfl_xor(sum, d, 64);
            if (row_l == 0)
                part[nt * (NB * S_LEN) + b * S_LEN + s] = sum;
        }
    }
}

// ---------------- K4: softmax over S per batch row (sums the 4 n-slices)
__global__ void k_softmax(const float* __restrict__ part,
                          float* __restrict__ weights) {
    int b = blockIdx.x, tid = threadIdx.x;  // 256 threads
    float v[8];
    float mx = -1e30f;
#pragma unroll
    for (int i = 0; i < 8; ++i) {
        int s = i * 256 + tid;
        float sc = part[0 * (NB * S_LEN) + b * S_LEN + s]
                 + part[1 * (NB * S_LEN) + b * S_LEN + s]
                 + part[2 * (NB * S_LEN) + b * S_LEN + s]
                 + part[3 * (NB * S_LEN) + b * S_LEN + s];
        v[i] = sc;
        mx = fmaxf(mx, sc);
    }
#pragma unroll
    for (int d = 1; d < 64; d <<= 1) mx = fmaxf(mx, __shfl_xor(mx, d, 64));
    __shared__ float sm[4], ss[4];
    if ((tid & 63) == 0) sm[tid >> 6] = mx;
    __syncthreads();
    mx = fmaxf(fmaxf(sm[0], sm[1]), fmaxf(sm[2], sm[3]));
    float sum = 0.f;
#pragma unroll
    for (int i = 0; i < 8; ++i) {
        v[i] = __expf(v[i] - mx);
        sum += v[i];
    }
#pragma unroll
    for (int d = 1; d < 64; d <<= 1) sum += __shfl_xor(sum, d, 64);
    if ((tid & 63) == 0) ss[tid >> 6] = sum;
    __syncthreads();
    sum = ss[0] + ss[1] + ss[2] + ss[3];
    float inv = 1.0f / sum;
#pragma unroll
    for (int i = 0; i < 8; ++i)
        weights[b * S_LEN + i * 256 + tid] = v[i] * inv;
}

// ---------------- K5 (bf16): context partials; thread t covers 8 elems
// grid (16 schunks, 32 b) x 256 thr; parity split over s within chunk
__global__ void k_ctx1b(const unsigned short* __restrict__ embB,
                        const float* __restrict__ weights,
                        float* __restrict__ cpart) {
    int sc = blockIdx.x, b = blockIdx.y, t = threadIdx.x;
    int par = t >> 7;
    int e0 = (t & 127) * 8;
    float acc[8] = {};
    int s0 = sc * 128;
    for (int i = 0; i < 128; i += 2) {
        int s = s0 + i + par;
        float w = weights[b * S_LEN + s];
        s16x8 x = *(const s16x8*)(embB + (((size_t)(s * NB + b)) << 10) + e0);
#pragma unroll
        for (int u = 0; u < 8; ++u)
            acc[u] += w * bf2f((unsigned short)x[u]);
    }
    float* dst = cpart + ((size_t)(sc * 2 + par) * NB + b) * EMB + e0;
    f32x4 lo = {acc[0], acc[1], acc[2], acc[3]};
    f32x4 hi = {acc[4], acc[5], acc[6], acc[7]};
    *(f32x4*)(dst)     = lo;
    *(f32x4*)(dst + 4) = hi;
}

__global__ void k_ctx2b(const float* __restrict__ cpart, float* __restrict__ ctx) {
    int i = blockIdx.x * 256 + threadIdx.x;   // 32*1024
    float s = 0.f;
#pragma unroll
    for (int p = 0; p < 32; ++p) s += cpart[(size_t)p * (NB * EMB) + i];
    ctx[i] = s;
}

// ---------------- f32 ctx fallback (round-2)
__global__ void k_ctx1(const float* __restrict__ emb,
                       const float* __restrict__ weights,
                       float* __restrict__ cpart) {
    int sc = blockIdx.x, b = blockIdx.y, t = threadIdx.x;
    const f32x4* ep = (const f32x4*)emb;
    f32x4 acc = {0.f, 0.f, 0.f, 0.f};
    int s0 = sc * 128;
    for (int i = 0; i < 128; i += 4) {
#pragma unroll
        for (int u = 0; u < 4; ++u) {
            int s = s0 + i + u;
            float w = weights[b * S_LEN + s];
            f32x4 x = ep[(size_t)(s * NB + b) * 256 + t];
            acc += w * x;
        }
    }
    ((f32x4*)cpart)[(size_t)(sc * NB + b) * 256 + t] = acc;
}
__global__ void k_ctx2(const float* __restrict__ cpart, float* __restrict__ ctx) {
    int i = blockIdx.x * 256 + threadIdx.x;
    float s = 0.f;
#pragma unroll
    for (int sc = 0; sc < 16; ++sc) s += cpart[sc * (NB * EMB) + i];
    ctx[i] = s;
}

extern "C" void kernel_launch(void* const* d_in, const int* in_sizes, int n_in,
                              void* d_out, int out_size, void* d_ws, size_t ws_size,
                              hipStream_t stream) {
    const float* hid   = (const float*)d_in[0];
    const float* emb   = (const float*)d_in[1];
    const float* W_hid = (const float*)d_in[2];
    const float* b_hid = (const float*)d_in[3];
    const float* W_emb = (const float*)d_in[4];
    const float* b_emb = (const float*)d_in[5];
    const float* att_v = (const float*)d_in[6];

    float* out     = (float*)d_out;
    float* ctx     = out;                // 32*1024
    float* weights = out + NB * EMB;     // 32*2048

    char* ws = (char*)d_ws;
    const size_t off_part  = 0;                       // 1 MiB
    const size_t off_hid   = 1048576;                 // 64 KiB
    const size_t off_WT    = 1114112;                 // 1 MiB
    const size_t off_embB  = 2162688;                 // 128 MiB
    const size_t off_cpart = off_embB + (size_t)134217728;  // 4 MiB
    const size_t need      = off_cpart + 4194304;

    float*          part     = (float*)(ws + off_part);
    float*          hid_comb = (float*)(ws + off_hid);
    unsigned short* WT       = (unsigned short*)(ws + off_WT);

    if (ws_size >= need) {
        unsigned short* embB  = (unsigned short*)(ws + off_embB);
        float*          cpart = (float*)(ws + off_cpart);
        k_cvt<<<2048, 256, 0, stream>>>(emb, embB);
        k_hidcomb<<<64, 256, 0, stream>>>(hid, W_hid, b_hid, b_emb, hid_comb);
        k_wt<<<dim3(32, 16), dim3(32, 8), 0, stream>>>(W_emb, WT);
        k_gemm_bf16<<<2048, 256, 0, stream>>>(embB, WT, hid_comb, att_v, part);
        k_softmax<<<NB, 256, 0, stream>>>(part, weights);
        k_ctx1b<<<dim3(16, NB), 256, 0, stream>>>(embB, weights, cpart);
        k_ctx2b<<<128, 256, 0, stream>>>(cpart, ctx);
    } else {
        float* cpart = (float*)(ws + off_WT);  // reuse WT space after gemm
        k_hidcomb<<<64, 256, 0, stream>>>(hid, W_hid, b_hid, b_emb, hid_comb);
        k_wt<<<dim3(32, 16), dim3(32, 8), 0, stream>>>(W_emb, WT);
        k_gemm_f32<<<2048, 256, 0, stream>>>(emb, WT, hid_comb, att_v, part);
        k_softmax<<<NB, 256, 0, stream>>>(part, weights);
        k_ctx1<<<dim3(16, NB), 256, 0, stream>>>(emb, weights, cpart);
        k_ctx2<<<128, 256, 0, stream>>>(cpart, ctx);
    }
}

// Round 4
// 267.919 us; speedup vs baseline: 1.1869x; 1.1869x over previous
//
#include <hip/hip_runtime.h>
#include <hip/hip_bf16.h>

#define S_LEN 2048
#define NB    32      // batch
#define EMB   1024
#define ATT   512
#define HID   1024

typedef float f32x4  __attribute__((ext_vector_type(4)));
typedef short s16x4  __attribute__((ext_vector_type(4)));
typedef short s16x8  __attribute__((ext_vector_type(8)));

static __device__ __forceinline__ short f2bf(float f) {
    return __builtin_bit_cast(short, __float2bfloat16(f));
}
static __device__ __forceinline__ float tanh_fast(float x) {
    float e = __expf(2.0f * x);
    return 1.0f - 2.0f / (e + 1.0f);
}

#define GLOAD_LDS16(gp, lp)                                                   \
    __builtin_amdgcn_global_load_lds(                                         \
        (const __attribute__((address_space(1))) void*)(gp),                  \
        (__attribute__((address_space(3))) void*)(uintptr_t)(lp), 16, 0, 0)

// ---------------- K1: hid_comb[b][a] = hid[b,:]@W_hid[:,a] + b_hid[a] + b_emb[a]
__global__ void k_hidcomb(const float* __restrict__ hid,
                          const float* __restrict__ W_hid,
                          const float* __restrict__ b_hid,
                          const float* __restrict__ b_emb,
                          float* __restrict__ hid_comb) {
    int gid = blockIdx.x * 256 + threadIdx.x;   // 32*512 = 16384
    int b = gid >> 9, a = gid & 511;
    const float* hr = hid + b * HID;
    float acc = 0.f;
#pragma unroll 4
    for (int k = 0; k < HID; ++k) acc += hr[k] * W_hid[k * ATT + a];
    hid_comb[gid] = acc + b_hid[a] + b_emb[a];
}

// ---------------- K2: W_T[a][k] = bf16(W_emb[k][a])
__global__ void k_wt(const float* __restrict__ W, unsigned short* __restrict__ WT) {
    __shared__ float tile[32][33];
    int k0 = blockIdx.x * 32, a0 = blockIdx.y * 32;
    int tx = threadIdx.x, ty = threadIdx.y;     // 32 x 8
#pragma unroll
    for (int i = 0; i < 32; i += 8)
        tile[ty + i][tx] = W[(size_t)(k0 + ty + i) * ATT + a0 + tx];
    __syncthreads();
#pragma unroll
    for (int i = 0; i < 32; i += 8)
        WT[(size_t)(a0 + ty + i) * HID + k0 + tx] =
            (unsigned short)f2bf(tile[tx][ty + i]);
}

// ---------------- K3: 128x128 GEMM, dbuf LDS + counted vmcnt (T3/T4 minimum
// 2-phase). A staged as f32 via global_load_lds (cvt->bf16 at frag read),
// B bf16 via global_load_lds. Fused tanh+dot(att_v) epilogue.
// 4 waves x (32x128) wave-slice -> no cross-wave combine, no atomics.
__global__ __launch_bounds__(256, 3) void k_gemm_scores(
        const float* __restrict__ emb,
        const unsigned short* __restrict__ WT,
        const float* __restrict__ hid_comb,
        const float* __restrict__ att_v,
        float* __restrict__ part) {           // part[nt][b][s], nt=0..3
    // double-buffered: A f32 [2][128][32] (16KB each), B bf16 [2][128][32] (8KB each)
    __shared__ __align__(16) float          lA[2 * 128 * 32];
    __shared__ __align__(16) unsigned short lB[2 * 128 * 32];

    // XCD swizzle: 2048 wgs, 8 XCDs; all 4 n-tiles of an m-panel on one XCD.
    int bid = blockIdx.x;
    int t2 = (bid & 7) * 256 + (bid >> 3);
    int mt = t2 >> 2, nt = t2 & 3;
    int m0 = mt * 128, n0 = nt * 128;

    int tid  = threadIdx.x;
    int lane = tid & 63, wave = tid >> 6;
    int row_l = lane & 15;        // fragment row (A) / col (B,D)
    int kg    = lane >> 4;        // k-group: k = kg*8 + i

    // ---- staging maps (pre-swizzled global source, linear LDS dest)
    // A: 128 rows x 8 chunks(16B) = 1024 chunks; 4 per thread
    const float* aSrc[4];
    int aDst[4];
#pragma unroll
    for (int j = 0; j < 4; ++j) {
        int c = j * 256 + tid;
        int r = c >> 3, pos = c & 7;
        int srcch = pos ^ (r & 7);
        aSrc[j] = emb + (size_t)(m0 + r) * EMB + srcch * 4;
        aDst[j] = c * 16;
    }
    // B: 128 rows x 4 chunks(16B) = 512 chunks; 2 per thread
    const unsigned short* bSrc[2];
    int bDst[2];
#pragma unroll
    for (int j = 0; j < 2; ++j) {
        int c = j * 256 + tid;
        int r = c >> 2, pos = c & 3;
        int srcch = pos ^ ((r >> 1) & 3);
        bSrc[j] = WT + (size_t)(n0 + r) * HID + srcch * 8;
        bDst[j] = c * 16;
    }

    // ---- fragment read byte-offsets (swizzled, within one buffer)
    int aoff[2][2], boff[8];
#pragma unroll
    for (int mf = 0; mf < 2; ++mf) {
        int row = wave * 32 + mf * 16 + row_l;
#pragma unroll
        for (int h = 0; h < 2; ++h)
            aoff[mf][h] = row * 128 + (((2 * kg + h) ^ (row & 7)) * 16);
    }
#pragma unroll
    for (int nf = 0; nf < 8; ++nf) {
        int row = nf * 16 + row_l;
        boff[nf] = row * 64 + ((kg ^ ((row >> 1) & 3)) * 16);
    }

    f32x4 acc[2][8] = {};

    // ---- prologue: stage tile 0 into buffer 0 (6 loads)
#pragma unroll
    for (int j = 0; j < 4; ++j) GLOAD_LDS16(aSrc[j], (char*)lA + aDst[j]);
#pragma unroll
    for (int j = 0; j < 2; ++j) GLOAD_LDS16(bSrc[j], (char*)lB + bDst[j]);

    int cur = 0;
    for (int kk = 0; kk < EMB; kk += 32) {
        // stage NEXT tile into the other buffer (wraps at end; dangling loads harmless)
        int nk = kk + 32; if (nk == EMB) nk = 0;
        int nxt = cur ^ 1;
#pragma unroll
        for (int j = 0; j < 4; ++j)
            GLOAD_LDS16(aSrc[j] + nk, (char*)lA + nxt * 16384 + aDst[j]);
#pragma unroll
        for (int j = 0; j < 2; ++j)
            GLOAD_LDS16(bSrc[j] + nk, (char*)lB + nxt * 8192 + bDst[j]);

        // wait only for CURRENT tile's 6 loads (issued one iteration ago)
        asm volatile("s_waitcnt vmcnt(6)\n\ts_barrier" ::: "memory");

        const char* pa = (const char*)lA + cur * 16384;
        const char* pb = (const char*)lB + cur * 8192;
        s16x8 af[2], bf[8];
#pragma unroll
        for (int mf = 0; mf < 2; ++mf) {
            f32x4 x0 = *(const f32x4*)(pa + aoff[mf][0]);
            f32x4 x1 = *(const f32x4*)(pa + aoff[mf][1]);
            s16x8 r;
            r[0] = f2bf(x0[0]); r[1] = f2bf(x0[1]);
            r[2] = f2bf(x0[2]); r[3] = f2bf(x0[3]);
            r[4] = f2bf(x1[0]); r[5] = f2bf(x1[1]);
            r[6] = f2bf(x1[2]); r[7] = f2bf(x1[3]);
            af[mf] = r;
        }
#pragma unroll
        for (int nf = 0; nf < 8; ++nf)
            bf[nf] = *(const s16x8*)(pb + boff[nf]);
#pragma unroll
        for (int mf = 0; mf < 2; ++mf)
#pragma unroll
            for (int nf = 0; nf < 8; ++nf)
                acc[mf][nf] = __builtin_amdgcn_mfma_f32_16x16x32_bf16(
                    af[mf], bf[nf], acc[mf][nf], 0, 0, 0);

        // all waves done reading cur; next iter may overwrite it
        asm volatile("s_barrier" ::: "memory");
        cur = nxt;
    }

    // ---- epilogue
    float vv[8];
#pragma unroll
    for (int nf = 0; nf < 8; ++nf)
        vv[nf] = att_v[n0 + nf * 16 + row_l];

#pragma unroll
    for (int mf = 0; mf < 2; ++mf) {
#pragma unroll
        for (int j = 0; j < 4; ++j) {
            int m = m0 + wave * 32 + mf * 16 + kg * 4 + j;   // D row
            int b = m & 31;
            int s = m >> 5;
            const float* ad = hid_comb + b * ATT + n0;
            float sum = 0.f;
#pragma unroll
            for (int nf = 0; nf < 8; ++nf) {
                float x = acc[mf][nf][j] + ad[nf * 16 + row_l];
                sum += tanh_fast(x) * vv[nf];
            }
#pragma unroll
            for (int d = 1; d < 16; d <<= 1)
                sum += __shfl_xor(sum, d, 64);
            if (row_l == 0)
                part[nt * (NB * S_LEN) + b * S_LEN + s] = sum;
        }
    }
}

// ---------------- K4: softmax over S per batch row (sums the 4 n-slices)
__global__ void k_softmax(const float* __restrict__ part,
                          float* __restrict__ weights) {
    int b = blockIdx.x, tid = threadIdx.x;  // 256 threads
    float v[8];
    float mx = -1e30f;
#pragma unroll
    for (int i = 0; i < 8; ++i) {
        int s = i * 256 + tid;
        float sc = part[0 * (NB * S_LEN) + b * S_LEN + s]
                 + part[1 * (NB * S_LEN) + b * S_LEN + s]
                 + part[2 * (NB * S_LEN) + b * S_LEN + s]
                 + part[3 * (NB * S_LEN) + b * S_LEN + s];
        v[i] = sc;
        mx = fmaxf(mx, sc);
    }
#pragma unroll
    for (int d = 1; d < 64; d <<= 1) mx = fmaxf(mx, __shfl_xor(mx, d, 64));
    __shared__ float sm[4], ss[4];
    if ((tid & 63) == 0) sm[tid >> 6] = mx;
    __syncthreads();
    mx = fmaxf(fmaxf(sm[0], sm[1]), fmaxf(sm[2], sm[3]));
    float sum = 0.f;
#pragma unroll
    for (int i = 0; i < 8; ++i) {
        v[i] = __expf(v[i] - mx);
        sum += v[i];
    }
#pragma unroll
    for (int d = 1; d < 64; d <<= 1) sum += __shfl_xor(sum, d, 64);
    if ((tid & 63) == 0) ss[tid >> 6] = sum;
    __syncthreads();
    sum = ss[0] + ss[1] + ss[2] + ss[3];
    float inv = 1.0f / sum;
#pragma unroll
    for (int i = 0; i < 8; ++i)
        weights[b * S_LEN + i * 256 + tid] = v[i] * inv;
}

// ---------------- K5: context partials over s-chunks (f32 emb)
__global__ void k_ctx1(const float* __restrict__ emb,
                       const float* __restrict__ weights,
                       float* __restrict__ cpart) {
    int sc = blockIdx.x, b = blockIdx.y, t = threadIdx.x;
    const f32x4* ep = (const f32x4*)emb;
    f32x4 acc = {0.f, 0.f, 0.f, 0.f};
    int s0 = sc * 128;
    for (int i = 0; i < 128; i += 4) {
#pragma unroll
        for (int u = 0; u < 4; ++u) {
            int s = s0 + i + u;
            float w = weights[b * S_LEN + s];
            f32x4 x = ep[(size_t)(s * NB + b) * 256 + t];
            acc += w * x;
        }
    }
    ((f32x4*)cpart)[(size_t)(sc * NB + b) * 256 + t] = acc;
}

// ---------------- K6: reduce partials -> context (d_out front)
__global__ void k_ctx2(const float* __restrict__ cpart, float* __restrict__ ctx) {
    int i = blockIdx.x * 256 + threadIdx.x;   // 32*1024
    float s = 0.f;
#pragma unroll
    for (int sc = 0; sc < 16; ++sc) s += cpart[sc * (NB * EMB) + i];
    ctx[i] = s;
}

extern "C" void kernel_launch(void* const* d_in, const int* in_sizes, int n_in,
                              void* d_out, int out_size, void* d_ws, size_t ws_size,
                              hipStream_t stream) {
    const float* hid   = (const float*)d_in[0];
    const float* emb   = (const float*)d_in[1];
    const float* W_hid = (const float*)d_in[2];
    const float* b_hid = (const float*)d_in[3];
    const float* W_emb = (const float*)d_in[4];
    const float* b_emb = (const float*)d_in[5];
    const float* att_v = (const float*)d_in[6];

    float* out     = (float*)d_out;
    float* ctx     = out;                // 32*1024
    float* weights = out + NB * EMB;     // 32*2048

    char* ws = (char*)d_ws;
    float*          part     = (float*)(ws);                    // 1 MiB
    float*          hid_comb = (float*)(ws + 1048576);          // 64 KiB
    unsigned short* WT       = (unsigned short*)(ws + 1114112); // 1 MiB
    float*          cpart    = (float*)(ws + 2162688);          // 2 MiB

    k_hidcomb<<<64, 256, 0, stream>>>(hid, W_hid, b_hid, b_emb, hid_comb);
    k_wt<<<dim3(32, 16), dim3(32, 8), 0, stream>>>(W_emb, WT);
    k_gemm_scores<<<2048, 256, 0, stream>>>(emb, WT, hid_comb, att_v, part);
    k_softmax<<<NB, 256, 0, stream>>>(part, weights);
    k_ctx1<<<dim3(16, NB), 256, 0, stream>>>(emb, weights, cpart);
    k_ctx2<<<128, 256, 0, stream>>>(cpart, ctx);
}